// Round 5
// baseline (252.879 us; speedup 1.0000x reference)
//
#include <hip/hip_runtime.h>
#include <hip/hip_bf16.h>

// Problem constants: B=8, T=1024, D=1024, H=16, HD=64
#define BATCH 8
#define SEQ   1024
#define DIM   1024
#define NH    16
#define HDIM  64
#define LDQKV 3072   // 3*DIM

typedef __attribute__((ext_vector_type(8))) short bf16x8;
typedef __attribute__((ext_vector_type(4))) float f32x4;

typedef const __attribute__((address_space(1))) void* gvptr;
typedef __attribute__((address_space(3))) void* lvptr;

static __device__ __forceinline__ short f2bf(float f) {
    unsigned u = __float_as_uint(f);
    unsigned r = (u + 0x7fffu + ((u >> 16) & 1u)) >> 16;   // RNE
    return (short)r;
}
// pack two fp32 -> bf16x2 dword (round-half-up)
static __device__ __forceinline__ unsigned pack2bf(float lo, float hi) {
    unsigned a = __float_as_uint(lo), b = __float_as_uint(hi);
    return ((a + 0x8000u) >> 16) | ((b + 0x8000u) & 0xffff0000u);
}

// ---------------------------------------------------------------------------
// cast fp32 -> bf16, 8 elems/thread
// ---------------------------------------------------------------------------
__global__ __launch_bounds__(256) void cast_f2b_kernel(
    const float* __restrict__ in, short* __restrict__ out)
{
    size_t i = ((size_t)blockIdx.x * 256 + threadIdx.x) * 8;
    float4 a = *(const float4*)&in[i];
    float4 b = *(const float4*)&in[i + 4];
    bf16x8 o;
    o[0] = f2bf(a.x); o[1] = f2bf(a.y); o[2] = f2bf(a.z); o[3] = f2bf(a.w);
    o[4] = f2bf(b.x); o[5] = f2bf(b.y); o[6] = f2bf(b.z); o[7] = f2bf(b.w);
    *(bf16x8*)&out[i] = o;
}

// ---------------------------------------------------------------------------
// transpose + cast: in [R x C] fp32 -> out [C x R] bf16.  32x32 tiles.
// ---------------------------------------------------------------------------
__global__ __launch_bounds__(256) void tcast_kernel(
    const float* __restrict__ in, short* __restrict__ out, int R, int C)
{
    __shared__ float Ld[32][33];
    const int tx = threadIdx.x & 31;
    const int ty = threadIdx.x >> 5;
    const int c0 = blockIdx.x * 32;
    const int r0 = blockIdx.y * 32;
#pragma unroll
    for (int i = 0; i < 4; i++) {
        int r = ty + i * 8;
        Ld[r][tx] = in[(size_t)(r0 + r) * C + c0 + tx];
    }
    __syncthreads();
#pragma unroll
    for (int i = 0; i < 4; i++) {
        int rr = ty + i * 8;
        out[(size_t)(c0 + rr) * R + r0 + tx] = f2bf(Ld[tx][rr]);
    }
}

// ---------------------------------------------------------------------------
// bf16 MFMA GEMM: C[M,N] = A[M,K] @ Bt[N,K]^T + bias[N]
// 128x128 tile, BK=32, 256 threads (4 waves 2x2), 4x4 16x16x32 acc per wave.
// LDS layout: [row][4 chunks of 16B], chunk c stored at slot c ^ ((row>>1)&3)
//   -> frag reads hit all 8 bank-quads per quarter-wave (conflict-free).
// Swapped MFMA operands (A-op=Bt, B-op=A): D reg axis = N -> each lane holds
//   4 consecutive n -> vectorized epilogue stores (8B bf16 / 16B fp32).
// ---------------------------------------------------------------------------
template<bool OUT_BF16>
__global__ __launch_bounds__(256) void gemm_mfma_kernel(
    const short* __restrict__ A,    // [M x K] bf16
    const short* __restrict__ Bt,   // [N x K] bf16
    const float* __restrict__ bias, // [N] fp32
    void* __restrict__ Cout,
    int M, int N, int K)
{
    __shared__ __align__(16) short As[128 * 32];
    __shared__ __align__(16) short Bs[128 * 32];

    const int tid  = threadIdx.x;
    const int w    = tid >> 6;
    const int lane = tid & 63;
    const int l16  = lane & 15;
    const int quad = lane >> 4;
    const int wm   = w >> 1;
    const int wn   = w & 1;
    const int m0   = blockIdx.y * 128;
    const int n0   = blockIdx.x * 128;

    // staging source chunk (XOR swizzle): dest slot s=vi&3 holds chunk s^((row>>1)&3)
    const int vi0   = tid;
    const int row0  = vi0 >> 2;
    const int src0  = ((vi0 & 3) ^ ((row0 >> 1) & 3)) * 8;
    const int vi1   = tid + 256;
    const int row1  = vi1 >> 2;
    const int src1  = ((vi1 & 3) ^ ((row1 >> 1) & 3)) * 8;

    f32x4 acc[4][4];
#pragma unroll
    for (int mi = 0; mi < 4; mi++)
#pragma unroll
        for (int ni = 0; ni < 4; ni++) acc[mi][ni] = (f32x4){0.f, 0.f, 0.f, 0.f};

    // frag-read offsets (swizzled slot per row)
    int aoff[4], boff[4];
#pragma unroll
    for (int i = 0; i < 4; i++) {
        int ra = wm * 64 + i * 16 + l16;
        aoff[i] = ra * 32 + (quad ^ ((ra >> 1) & 3)) * 8;
        int rb = wn * 64 + i * 16 + l16;
        boff[i] = rb * 32 + (quad ^ ((rb >> 1) & 3)) * 8;
    }

    for (int kt = 0; kt < K; kt += 32) {
        __syncthreads();
        __builtin_amdgcn_global_load_lds(
            (gvptr)&A[(size_t)(m0 + row0) * K + kt + src0], (lvptr)&As[vi0 * 8], 16, 0, 0);
        __builtin_amdgcn_global_load_lds(
            (gvptr)&A[(size_t)(m0 + row1) * K + kt + src1], (lvptr)&As[vi1 * 8], 16, 0, 0);
        __builtin_amdgcn_global_load_lds(
            (gvptr)&Bt[(size_t)(n0 + row0) * K + kt + src0], (lvptr)&Bs[vi0 * 8], 16, 0, 0);
        __builtin_amdgcn_global_load_lds(
            (gvptr)&Bt[(size_t)(n0 + row1) * K + kt + src1], (lvptr)&Bs[vi1 * 8], 16, 0, 0);
        __syncthreads();

        bf16x8 af[4], bfr[4];
#pragma unroll
        for (int mi = 0; mi < 4; mi++) af[mi]  = *(const bf16x8*)&As[aoff[mi]];
#pragma unroll
        for (int ni = 0; ni < 4; ni++) bfr[ni] = *(const bf16x8*)&Bs[boff[ni]];
        // swapped operands: D[i=n][j=m]
#pragma unroll
        for (int mi = 0; mi < 4; mi++)
#pragma unroll
            for (int ni = 0; ni < 4; ni++)
                acc[mi][ni] = __builtin_amdgcn_mfma_f32_16x16x32_bf16(
                    bfr[ni], af[mi], acc[mi][ni], 0, 0, 0);
    }

    // epilogue: m = m0+wm*64+mi*16+l16 (lane-fixed), n = n0+wn*64+ni*16+quad*4+reg
#pragma unroll
    for (int mi = 0; mi < 4; mi++) {
        int m = m0 + wm * 64 + mi * 16 + l16;
#pragma unroll
        for (int ni = 0; ni < 4; ni++) {
            int n = n0 + wn * 64 + ni * 16 + quad * 4;
            float4 bb = *(const float4*)&bias[n];
            float v0 = acc[mi][ni][0] + bb.x;
            float v1 = acc[mi][ni][1] + bb.y;
            float v2 = acc[mi][ni][2] + bb.z;
            float v3 = acc[mi][ni][3] + bb.w;
            if (OUT_BF16) {
                *(uint2*)&((short*)Cout)[(size_t)m * N + n] =
                    make_uint2(pack2bf(v0, v1), pack2bf(v2, v3));
            } else {
                *(float4*)&((float*)Cout)[(size_t)m * N + n] =
                    make_float4(v0, v1, v2, v3);
            }
        }
    }
}

// ---------------------------------------------------------------------------
// Causal flash attention v2 (unchanged from round 4): swapped-operand MFMA,
// static-max softmax, Q-tile 128, K-tile 64, bf16 in/out, fp32 acc.
// ---------------------------------------------------------------------------
#define LDK 72
#define LDP 72

__global__ __launch_bounds__(256, 4) void attn_kernel(
    const short* __restrict__ qkv, short* __restrict__ out)
{
    const int bh    = blockIdx.x;
    const int qtile = 7 - (int)blockIdx.y;
    const int b  = bh >> 4;
    const int h  = bh & 15;
    const int q0 = qtile * 128;
    const int tid  = threadIdx.x;
    const int w    = tid >> 6;
    const int lane = tid & 63;
    const int l16  = lane & 15;
    const int quad = lane >> 4;

    __shared__ __align__(16) short Ks[64 * LDK];
    __shared__ __align__(16) short Vt[64 * LDK];
    __shared__ __align__(16) short QP[128 * LDP];

    const short* qbase = qkv + (size_t)(b * SEQ + q0) * LDQKV + h * HDIM;
#pragma unroll
    for (int s = 0; s < 4; s++) {
        int vi = tid + s * 256;
        int row = vi >> 3, d8 = (vi & 7) * 8;
        *(bf16x8*)&QP[row * LDP + d8] =
            *(const bf16x8*)&qbase[(size_t)row * LDQKV + d8];
    }
    __syncthreads();

    bf16x8 qfragT[2][2];
#pragma unroll
    for (int qb = 0; qb < 2; qb++)
#pragma unroll
        for (int ks = 0; ks < 2; ks++)
            qfragT[qb][ks] = *(const bf16x8*)
                &QP[(w * 32 + qb * 16 + l16) * LDP + ks * 32 + quad * 8];

    f32x4 o_accT[2][4];
#pragma unroll
    for (int qb = 0; qb < 2; qb++)
#pragma unroll
        for (int db = 0; db < 4; db++) o_accT[qb][db] = (f32x4){0.f, 0.f, 0.f, 0.f};
    float l_run[2] = {0.f, 0.f};

    const int nkt = 2 * qtile + 2;
    const short* kb0 = qkv + (size_t)b * SEQ * LDQKV + DIM + h * HDIM;
    const short* vb0 = kb0 + DIM;

    const int vkey0 = (tid & 15) * 4;
    const int vd4   = (tid >> 4) * 4;

    bf16x8 kreg[2];
    short4 vreg[4];
#pragma unroll
    for (int s = 0; s < 2; s++) {
        int vi = tid + s * 256;
        kreg[s] = *(const bf16x8*)&kb0[(size_t)(vi >> 3) * LDQKV + (vi & 7) * 8];
    }
#pragma unroll
    for (int i = 0; i < 4; i++)
        vreg[i] = *(const short4*)&vb0[(size_t)(vkey0 + i) * LDQKV + vd4];
#pragma unroll
    for (int s = 0; s < 2; s++) {
        int vi = tid + s * 256;
        *(bf16x8*)&Ks[(vi >> 3) * LDK + (vi & 7) * 8] = kreg[s];
    }
    *(short4*)&Vt[(vd4 + 0) * LDK + vkey0] = make_short4(vreg[0].x, vreg[1].x, vreg[2].x, vreg[3].x);
    *(short4*)&Vt[(vd4 + 1) * LDK + vkey0] = make_short4(vreg[0].y, vreg[1].y, vreg[2].y, vreg[3].y);
    *(short4*)&Vt[(vd4 + 2) * LDK + vkey0] = make_short4(vreg[0].z, vreg[1].z, vreg[2].z, vreg[3].z);
    *(short4*)&Vt[(vd4 + 3) * LDK + vkey0] = make_short4(vreg[0].w, vreg[1].w, vreg[2].w, vreg[3].w);

    for (int kt = 0; kt < nkt; kt++) {
        __syncthreads();
        const int k0 = kt * 64;

        if (kt + 1 < nkt) {
            const short* kb = kb0 + (size_t)(k0 + 64) * LDQKV;
            const short* vb = vb0 + (size_t)(k0 + 64) * LDQKV;
#pragma unroll
            for (int s = 0; s < 2; s++) {
                int vi = tid + s * 256;
                kreg[s] = *(const bf16x8*)&kb[(size_t)(vi >> 3) * LDQKV + (vi & 7) * 8];
            }
#pragma unroll
            for (int i = 0; i < 4; i++)
                vreg[i] = *(const short4*)&vb[(size_t)(vkey0 + i) * LDQKV + vd4];
        }

        f32x4 sT[2][4];
#pragma unroll
        for (int qb = 0; qb < 2; qb++)
#pragma unroll
            for (int kb = 0; kb < 4; kb++) sT[qb][kb] = (f32x4){0.f, 0.f, 0.f, 0.f};
#pragma unroll
        for (int kb = 0; kb < 4; kb++) {
            bf16x8 kf0 = *(const bf16x8*)&Ks[(kb * 16 + l16) * LDK + quad * 8];
            bf16x8 kf1 = *(const bf16x8*)&Ks[(kb * 16 + l16) * LDK + 32 + quad * 8];
#pragma unroll
            for (int qb = 0; qb < 2; qb++) {
                sT[qb][kb] = __builtin_amdgcn_mfma_f32_16x16x32_bf16(
                    kf0, qfragT[qb][0], sT[qb][kb], 0, 0, 0);
                sT[qb][kb] = __builtin_amdgcn_mfma_f32_16x16x32_bf16(
                    kf1, qfragT[qb][1], sT[qb][kb], 0, 0, 0);
            }
        }

        const bool domask = (kt >= nkt - 2);
#pragma unroll
        for (int qb = 0; qb < 2; qb++) {
            const int q = q0 + w * 32 + qb * 16 + l16;
            float lsum = 0.f;
#pragma unroll
            for (int kb = 0; kb < 4; kb++) {
                float p[4];
#pragma unroll
                for (int r = 0; r < 4; r++) {
                    float e = __expf(sT[qb][kb][r] * 0.125f);
                    int key = k0 + kb * 16 + quad * 4 + r;
                    p[r] = (!domask || key <= q) ? e : 0.f;
                    lsum += p[r];
                }
                unsigned d0 = pack2bf(p[0], p[1]);
                unsigned d1 = pack2bf(p[2], p[3]);
                *(uint2*)&QP[(w * 32 + qb * 16 + l16) * LDP + kb * 16 + quad * 4] =
                    make_uint2(d0, d1);
            }
            lsum += __shfl_xor(lsum, 16, 64);
            lsum += __shfl_xor(lsum, 32, 64);
            l_run[qb] += lsum;
        }

#pragma unroll
        for (int ks2 = 0; ks2 < 2; ks2++) {
            bf16x8 pf[2];
#pragma unroll
            for (int qb = 0; qb < 2; qb++)
                pf[qb] = *(const bf16x8*)
                    &QP[(w * 32 + qb * 16 + l16) * LDP + ks2 * 32 + quad * 8];
#pragma unroll
            for (int db = 0; db < 4; db++) {
                bf16x8 vf = *(const bf16x8*)&Vt[(db * 16 + l16) * LDK + ks2 * 32 + quad * 8];
#pragma unroll
                for (int qb = 0; qb < 2; qb++)
                    o_accT[qb][db] = __builtin_amdgcn_mfma_f32_16x16x32_bf16(
                        vf, pf[qb], o_accT[qb][db], 0, 0, 0);
            }
        }

        __syncthreads();
        if (kt + 1 < nkt) {
#pragma unroll
            for (int s = 0; s < 2; s++) {
                int vi = tid + s * 256;
                *(bf16x8*)&Ks[(vi >> 3) * LDK + (vi & 7) * 8] = kreg[s];
            }
            *(short4*)&Vt[(vd4 + 0) * LDK + vkey0] = make_short4(vreg[0].x, vreg[1].x, vreg[2].x, vreg[3].x);
            *(short4*)&Vt[(vd4 + 1) * LDK + vkey0] = make_short4(vreg[0].y, vreg[1].y, vreg[2].y, vreg[3].y);
            *(short4*)&Vt[(vd4 + 2) * LDK + vkey0] = make_short4(vreg[0].z, vreg[1].z, vreg[2].z, vreg[3].z);
            *(short4*)&Vt[(vd4 + 3) * LDK + vkey0] = make_short4(vreg[0].w, vreg[1].w, vreg[2].w, vreg[3].w);
        }
    }

#pragma unroll
    for (int qb = 0; qb < 2; qb++) {
        const float inv = 1.f / l_run[qb];
        const int q = q0 + w * 32 + qb * 16 + l16;
        short* ob = out + (size_t)(b * SEQ + q) * DIM + h * HDIM;
#pragma unroll
        for (int db = 0; db < 4; db++) {
            float v0 = o_accT[qb][db][0] * inv;
            float v1 = o_accT[qb][db][1] * inv;
            float v2 = o_accT[qb][db][2] * inv;
            float v3 = o_accT[qb][db][3] * inv;
            *(uint2*)&ob[db * 16 + quad * 4] =
                make_uint2(pack2bf(v0, v1), pack2bf(v2, v3));
        }
    }
}

// ---------------------------------------------------------------------------
extern "C" void kernel_launch(void* const* d_in, const int* in_sizes, int n_in,
                              void* d_out, int out_size, void* d_ws, size_t ws_size,
                              hipStream_t stream)
{
    const float* x      = (const float*)d_in[0];
    const float* w_qkv  = (const float*)d_in[1];
    const float* b_qkv  = (const float*)d_in[2];
    const float* w_proj = (const float*)d_in[3];
    const float* b_proj = (const float*)d_in[4];
    float* out = (float*)d_out;

    const int M = BATCH * SEQ;  // 8192

    short* xb    = (short*)d_ws;
    short* wqb   = xb   + (size_t)M * DIM;
    short* wpb   = wqb  + (size_t)LDQKV * DIM;
    short* qkvb  = wpb  + (size_t)DIM * DIM;
    short* attnb = qkvb + (size_t)M * LDQKV;

    cast_f2b_kernel<<<(M * DIM) / (256 * 8), 256, 0, stream>>>(x, xb);
    tcast_kernel<<<dim3(LDQKV / 32, DIM / 32), 256, 0, stream>>>(w_qkv, wqb, DIM, LDQKV);
    tcast_kernel<<<dim3(DIM / 32, DIM / 32), 256, 0, stream>>>(w_proj, wpb, DIM, DIM);

    gemm_mfma_kernel<true><<<dim3(LDQKV / 128, M / 128), 256, 0, stream>>>(
        xb, wqb, b_qkv, (void*)qkvb, M, LDQKV, DIM);

    attn_kernel<<<dim3(BATCH * NH, SEQ / 128), 256, 0, stream>>>(qkvb, attnb);

    gemm_mfma_kernel<false><<<dim3(DIM / 128, M / 128), 256, 0, stream>>>(
        attnb, wpb, b_proj, (void*)out, M, DIM, DIM);
}

// Round 6
// 249.828 us; speedup vs baseline: 1.0122x; 1.0122x over previous
//
#include <hip/hip_runtime.h>
#include <hip/hip_bf16.h>

// Problem constants: B=8, T=1024, D=1024, H=16, HD=64
#define BATCH 8
#define SEQ   1024
#define DIM   1024
#define NH    16
#define HDIM  64
#define LDQKV 3072   // 3*DIM

typedef __attribute__((ext_vector_type(8))) short bf16x8;
typedef __attribute__((ext_vector_type(4))) float f32x4;

typedef const __attribute__((address_space(1))) void* gvptr;
typedef __attribute__((address_space(3))) void* lvptr;

static __device__ __forceinline__ short f2bf(float f) {
    unsigned u = __float_as_uint(f);
    unsigned r = (u + 0x7fffu + ((u >> 16) & 1u)) >> 16;   // RNE
    return (short)r;
}
// pack two fp32 -> bf16x2 dword (round-half-up)
static __device__ __forceinline__ unsigned pack2bf(float lo, float hi) {
    unsigned a = __float_as_uint(lo), b = __float_as_uint(hi);
    return ((a + 0x8000u) >> 16) | ((b + 0x8000u) & 0xffff0000u);
}

// ---------------------------------------------------------------------------
// cast fp32 -> bf16, 8 elems/thread
// ---------------------------------------------------------------------------
__global__ __launch_bounds__(256) void cast_f2b_kernel(
    const float* __restrict__ in, short* __restrict__ out)
{
    size_t i = ((size_t)blockIdx.x * 256 + threadIdx.x) * 8;
    float4 a = *(const float4*)&in[i];
    float4 b = *(const float4*)&in[i + 4];
    bf16x8 o;
    o[0] = f2bf(a.x); o[1] = f2bf(a.y); o[2] = f2bf(a.z); o[3] = f2bf(a.w);
    o[4] = f2bf(b.x); o[5] = f2bf(b.y); o[6] = f2bf(b.z); o[7] = f2bf(b.w);
    *(bf16x8*)&out[i] = o;
}

// ---------------------------------------------------------------------------
// transpose + cast: in [R x C] fp32 -> out [C x R] bf16.  32x32 tiles.
// ---------------------------------------------------------------------------
__global__ __launch_bounds__(256) void tcast_kernel(
    const float* __restrict__ in, short* __restrict__ out, int R, int C)
{
    __shared__ float Ld[32][33];
    const int tx = threadIdx.x & 31;
    const int ty = threadIdx.x >> 5;
    const int c0 = blockIdx.x * 32;
    const int r0 = blockIdx.y * 32;
#pragma unroll
    for (int i = 0; i < 4; i++) {
        int r = ty + i * 8;
        Ld[r][tx] = in[(size_t)(r0 + r) * C + c0 + tx];
    }
    __syncthreads();
#pragma unroll
    for (int i = 0; i < 4; i++) {
        int rr = ty + i * 8;
        out[(size_t)(c0 + rr) * R + r0 + tx] = f2bf(Ld[tx][rr]);
    }
}

// ---------------------------------------------------------------------------
// V transpose (bf16): qkv V-section [key][d] per (b,h) -> VtG[b,h][d][key].
// Grid: (128 bh, 16 key-tiles).  Coalesced b128 in and out.
// ---------------------------------------------------------------------------
__global__ __launch_bounds__(256) void vtrans_kernel(
    const short* __restrict__ qkv, short* __restrict__ VtG)
{
    const int bh = blockIdx.x;
    const int kt = blockIdx.y;
    const int b  = bh >> 4;
    const int h  = bh & 15;
    __shared__ __align__(16) short Ld[64 * 72];

    const short* src = qkv + (size_t)(b * SEQ + kt * 64) * LDQKV + 2 * DIM + h * HDIM;
#pragma unroll
    for (int s = 0; s < 2; s++) {
        int vi = (int)threadIdx.x + s * 256;
        int row = vi >> 3, ch = (vi & 7) * 8;
        *(bf16x8*)&Ld[row * 72 + ch] =
            *(const bf16x8*)&src[(size_t)row * LDQKV + ch];
    }
    __syncthreads();
#pragma unroll
    for (int s = 0; s < 2; s++) {
        int vi = (int)threadIdx.x + s * 256;
        int d = vi >> 3, kc = (vi & 7) * 8;
        bf16x8 o;
#pragma unroll
        for (int j = 0; j < 8; j++) o[j] = Ld[(kc + j) * 72 + d];
        *(bf16x8*)&VtG[((size_t)bh * HDIM + d) * SEQ + kt * 64 + kc] = o;
    }
}

// ---------------------------------------------------------------------------
// bf16 MFMA GEMM (round-4 version, reverted): C = A @ Bt^T + bias
// 128x128 tile, BK=32, 256 threads (4 waves 2x2), 4x4 16x16x32 acc per wave.
// ---------------------------------------------------------------------------
template<bool OUT_BF16>
__global__ __launch_bounds__(256) void gemm_mfma_kernel(
    const short* __restrict__ A,    // [M x K] bf16
    const short* __restrict__ Bt,   // [N x K] bf16
    const float* __restrict__ bias, // [N] fp32
    void* __restrict__ Cout,
    int M, int N, int K)
{
    __shared__ __align__(16) short As[128 * 32];
    __shared__ __align__(16) short Bs[128 * 32];

    const int tid  = threadIdx.x;
    const int w    = tid >> 6;
    const int lane = tid & 63;
    const int l16  = lane & 15;
    const int quad = lane >> 4;
    const int wm   = w >> 1;
    const int wn   = w & 1;
    const int m0   = blockIdx.y * 128;
    const int n0   = blockIdx.x * 128;

    f32x4 acc[4][4];
#pragma unroll
    for (int mi = 0; mi < 4; mi++)
#pragma unroll
        for (int ni = 0; ni < 4; ni++) acc[mi][ni] = (f32x4){0.f, 0.f, 0.f, 0.f};

    for (int kt = 0; kt < K; kt += 32) {
        __syncthreads();
#pragma unroll
        for (int r = 0; r < 2; r++) {
            int vi  = tid + r * 256;
            int row = vi >> 2;
            int kb  = (vi & 3) * 8;
            __builtin_amdgcn_global_load_lds(
                (gvptr)&A[(size_t)(m0 + row) * K + kt + kb],
                (lvptr)&As[vi * 8], 16, 0, 0);
        }
#pragma unroll
        for (int r = 0; r < 2; r++) {
            int vi  = tid + r * 256;
            int row = vi >> 2;
            int kb  = (vi & 3) * 8;
            __builtin_amdgcn_global_load_lds(
                (gvptr)&Bt[(size_t)(n0 + row) * K + kt + kb],
                (lvptr)&Bs[vi * 8], 16, 0, 0);
        }
        __syncthreads();

        bf16x8 af[4], bfr[4];
#pragma unroll
        for (int mi = 0; mi < 4; mi++)
            af[mi] = *(const bf16x8*)&As[(wm * 64 + mi * 16 + l16) * 32 + quad * 8];
#pragma unroll
        for (int ni = 0; ni < 4; ni++)
            bfr[ni] = *(const bf16x8*)&Bs[(wn * 64 + ni * 16 + l16) * 32 + quad * 8];
#pragma unroll
        for (int mi = 0; mi < 4; mi++)
#pragma unroll
            for (int ni = 0; ni < 4; ni++)
                acc[mi][ni] = __builtin_amdgcn_mfma_f32_16x16x32_bf16(
                    af[mi], bfr[ni], acc[mi][ni], 0, 0, 0);
    }

#pragma unroll
    for (int ni = 0; ni < 4; ni++) {
        int n = n0 + wn * 64 + ni * 16 + l16;
        float bv = bias[n];
#pragma unroll
        for (int mi = 0; mi < 4; mi++) {
#pragma unroll
            for (int reg = 0; reg < 4; reg++) {
                int m = m0 + wm * 64 + mi * 16 + quad * 4 + reg;
                float v = acc[mi][ni][reg] + bv;
                if (OUT_BF16)
                    ((short*)Cout)[(size_t)m * N + n] = f2bf(v);
                else
                    ((float*)Cout)[(size_t)m * N + n] = v;
            }
        }
    }
}

// ---------------------------------------------------------------------------
// Causal flash attention v3: swapped-operand MFMA, static-max softmax,
// Q-tile 128, K-tile 64, bf16 in/out, fp32 acc.  V comes pre-transposed
// (VtG[b,h][d][key]) so both K and Vt stage as coalesced b128 prefetches.
// ---------------------------------------------------------------------------
#define LDK 72
#define LDP 72

__global__ __launch_bounds__(256, 4) void attn_kernel(
    const short* __restrict__ qkv, const short* __restrict__ VtG,
    short* __restrict__ out)
{
    const int bh    = blockIdx.x;
    const int qtile = 7 - (int)blockIdx.y;      // longest first
    const int b  = bh >> 4;
    const int h  = bh & 15;
    const int q0 = qtile * 128;
    const int tid  = threadIdx.x;
    const int w    = tid >> 6;
    const int lane = tid & 63;
    const int l16  = lane & 15;
    const int quad = lane >> 4;

    __shared__ __align__(16) short Ks[64 * LDK];
    __shared__ __align__(16) short Vt[64 * LDK];   // [d][key]
    __shared__ __align__(16) short QP[128 * LDP];  // Q staging, then wave-private P

    // ---- stage Q (128 x 64 bf16) ----
    const short* qbase = qkv + (size_t)(b * SEQ + q0) * LDQKV + h * HDIM;
#pragma unroll
    for (int s = 0; s < 4; s++) {
        int vi = tid + s * 256;
        int row = vi >> 3, d8 = (vi & 7) * 8;
        *(bf16x8*)&QP[row * LDP + d8] =
            *(const bf16x8*)&qbase[(size_t)row * LDQKV + d8];
    }
    __syncthreads();

    bf16x8 qfragT[2][2];
#pragma unroll
    for (int qb = 0; qb < 2; qb++)
#pragma unroll
        for (int ks = 0; ks < 2; ks++)
            qfragT[qb][ks] = *(const bf16x8*)
                &QP[(w * 32 + qb * 16 + l16) * LDP + ks * 32 + quad * 8];
    // From here QP rows are wave-private.

    f32x4 o_accT[2][4];
#pragma unroll
    for (int qb = 0; qb < 2; qb++)
#pragma unroll
        for (int db = 0; db < 4; db++) o_accT[qb][db] = (f32x4){0.f, 0.f, 0.f, 0.f};
    float l_run[2] = {0.f, 0.f};

    const int nkt = 2 * qtile + 2;
    const short* kb0 = qkv + (size_t)b * SEQ * LDQKV + DIM + h * HDIM;
    const short* vtb = VtG + (size_t)bh * HDIM * SEQ;   // [64][1024]

    const int srow = tid >> 3;          // 0..63 (with s-offset covers 64 rows x 8 chunks)
    const int sch  = (tid & 7) * 8;     // key/dim chunk base

    bf16x8 kreg[2], vreg[2];
    // prefetch + stage tile 0
#pragma unroll
    for (int s = 0; s < 2; s++) {
        int vi = tid + s * 256;
        int row = vi >> 3, ch = (vi & 7) * 8;
        kreg[s] = *(const bf16x8*)&kb0[(size_t)row * LDQKV + ch];
        vreg[s] = *(const bf16x8*)&vtb[(size_t)row * SEQ + ch];
    }
#pragma unroll
    for (int s = 0; s < 2; s++) {
        int vi = tid + s * 256;
        int row = vi >> 3, ch = (vi & 7) * 8;
        *(bf16x8*)&Ks[row * LDK + ch] = kreg[s];
        *(bf16x8*)&Vt[row * LDK + ch] = vreg[s];
    }

    for (int kt = 0; kt < nkt; kt++) {
        __syncthreads();            // Ks/Vt tile visible to all waves
        const int k0 = kt * 64;

        // prefetch next tile into registers (overlaps compute)
        if (kt + 1 < nkt) {
            const short* kb = kb0 + (size_t)(k0 + 64) * LDQKV;
            const short* vb = vtb + k0 + 64;
#pragma unroll
            for (int s = 0; s < 2; s++) {
                int vi = tid + s * 256;
                int row = vi >> 3, ch = (vi & 7) * 8;
                kreg[s] = *(const bf16x8*)&kb[(size_t)row * LDQKV + ch];
                vreg[s] = *(const bf16x8*)&vb[(size_t)row * SEQ + ch];
            }
        }

        // ---- S^T = K Q^T : A=K frag (m=key), B=Q frag (n=q) ----
        f32x4 sT[2][4];
#pragma unroll
        for (int qb = 0; qb < 2; qb++)
#pragma unroll
            for (int kb = 0; kb < 4; kb++) sT[qb][kb] = (f32x4){0.f, 0.f, 0.f, 0.f};
#pragma unroll
        for (int kb = 0; kb < 4; kb++) {
            bf16x8 kf0 = *(const bf16x8*)&Ks[(kb * 16 + l16) * LDK + quad * 8];
            bf16x8 kf1 = *(const bf16x8*)&Ks[(kb * 16 + l16) * LDK + 32 + quad * 8];
#pragma unroll
            for (int qb = 0; qb < 2; qb++) {
                sT[qb][kb] = __builtin_amdgcn_mfma_f32_16x16x32_bf16(
                    kf0, qfragT[qb][0], sT[qb][kb], 0, 0, 0);
                sT[qb][kb] = __builtin_amdgcn_mfma_f32_16x16x32_bf16(
                    kf1, qfragT[qb][1], sT[qb][kb], 0, 0, 0);
            }
        }

        // ---- exp, causal mask (last 2 tiles only), pack, write P, l partial ----
        const bool domask = (kt >= nkt - 2);
#pragma unroll
        for (int qb = 0; qb < 2; qb++) {
            const int q = q0 + w * 32 + qb * 16 + l16;
            float lsum = 0.f;
#pragma unroll
            for (int kb = 0; kb < 4; kb++) {
                float p[4];
#pragma unroll
                for (int r = 0; r < 4; r++) {
                    float e = __expf(sT[qb][kb][r] * 0.125f);
                    int key = k0 + kb * 16 + quad * 4 + r;
                    p[r] = (!domask || key <= q) ? e : 0.f;
                    lsum += p[r];
                }
                unsigned d0 = pack2bf(p[0], p[1]);
                unsigned d1 = pack2bf(p[2], p[3]);
                *(uint2*)&QP[(w * 32 + qb * 16 + l16) * LDP + kb * 16 + quad * 4] =
                    make_uint2(d0, d1);
            }
            lsum += __shfl_xor(lsum, 16, 64);
            lsum += __shfl_xor(lsum, 32, 64);
            l_run[qb] += lsum;
        }

        // ---- O^T += V^T P^T : A=Vt frag (m=d), B=P frag (n=q) ----
#pragma unroll
        for (int ks2 = 0; ks2 < 2; ks2++) {
            bf16x8 pf[2];
#pragma unroll
            for (int qb = 0; qb < 2; qb++)
                pf[qb] = *(const bf16x8*)
                    &QP[(w * 32 + qb * 16 + l16) * LDP + ks2 * 32 + quad * 8];
#pragma unroll
            for (int db = 0; db < 4; db++) {
                bf16x8 vf = *(const bf16x8*)&Vt[(db * 16 + l16) * LDK + ks2 * 32 + quad * 8];
#pragma unroll
                for (int qb = 0; qb < 2; qb++)
                    o_accT[qb][db] = __builtin_amdgcn_mfma_f32_16x16x32_bf16(
                        vf, pf[qb], o_accT[qb][db], 0, 0, 0);
            }
        }

        __syncthreads();            // compute done; Ks/Vt free for restage
        if (kt + 1 < nkt) {
#pragma unroll
            for (int s = 0; s < 2; s++) {
                int vi = tid + s * 256;
                int row = vi >> 3, ch = (vi & 7) * 8;
                *(bf16x8*)&Ks[row * LDK + ch] = kreg[s];
                *(bf16x8*)&Vt[row * LDK + ch] = vreg[s];
            }
        }
    }

    // ---- epilogue: O^T/l, packed 8B stores ----
#pragma unroll
    for (int qb = 0; qb < 2; qb++) {
        const float inv = 1.f / l_run[qb];
        const int q = q0 + w * 32 + qb * 16 + l16;
        short* ob = out + (size_t)(b * SEQ + q) * DIM + h * HDIM;
#pragma unroll
        for (int db = 0; db < 4; db++) {
            float v0 = o_accT[qb][db][0] * inv;
            float v1 = o_accT[qb][db][1] * inv;
            float v2 = o_accT[qb][db][2] * inv;
            float v3 = o_accT[qb][db][3] * inv;
            *(uint2*)&ob[db * 16 + quad * 4] =
                make_uint2(pack2bf(v0, v1), pack2bf(v2, v3));
        }
    }
}

// ---------------------------------------------------------------------------
extern "C" void kernel_launch(void* const* d_in, const int* in_sizes, int n_in,
                              void* d_out, int out_size, void* d_ws, size_t ws_size,
                              hipStream_t stream)
{
    const float* x      = (const float*)d_in[0];
    const float* w_qkv  = (const float*)d_in[1];
    const float* b_qkv  = (const float*)d_in[2];
    const float* w_proj = (const float*)d_in[3];
    const float* b_proj = (const float*)d_in[4];
    float* out = (float*)d_out;

    const int M = BATCH * SEQ;  // 8192

    short* xb    = (short*)d_ws;                       // [8192 x 1024]
    short* wqb   = xb    + (size_t)M * DIM;            // [3072 x 1024]
    short* wpb   = wqb   + (size_t)LDQKV * DIM;        // [1024 x 1024]
    short* qkvb  = wpb   + (size_t)DIM * DIM;          // [8192 x 3072]
    short* attnb = qkvb  + (size_t)M * LDQKV;          // [8192 x 1024]
    short* vtg   = attnb + (size_t)M * DIM;            // [128 x 64 x 1024]

    cast_f2b_kernel<<<(M * DIM) / (256 * 8), 256, 0, stream>>>(x, xb);
    tcast_kernel<<<dim3(LDQKV / 32, DIM / 32), 256, 0, stream>>>(w_qkv, wqb, DIM, LDQKV);
    tcast_kernel<<<dim3(DIM / 32, DIM / 32), 256, 0, stream>>>(w_proj, wpb, DIM, DIM);

    gemm_mfma_kernel<true><<<dim3(LDQKV / 128, M / 128), 256, 0, stream>>>(
        xb, wqb, b_qkv, (void*)qkvb, M, LDQKV, DIM);

    vtrans_kernel<<<dim3(BATCH * NH, SEQ / 64), 256, 0, stream>>>(qkvb, vtg);

    attn_kernel<<<dim3(BATCH * NH, SEQ / 128), 256, 0, stream>>>(qkvb, vtg, attnb);

    gemm_mfma_kernel<false><<<dim3(DIM / 128, M / 128), 256, 0, stream>>>(
        attnb, wpb, b_proj, (void*)out, M, DIM, DIM);
}

// Round 7
// 239.175 us; speedup vs baseline: 1.0573x; 1.0445x over previous
//
#include <hip/hip_runtime.h>
#include <hip/hip_bf16.h>

// Problem constants: B=8, T=1024, D=1024, H=16, HD=64
#define BATCH 8
#define SEQ   1024
#define DIM   1024
#define NH    16
#define HDIM  64
#define LDQKV 3072   // 3*DIM

typedef __attribute__((ext_vector_type(8))) short bf16x8;
typedef __attribute__((ext_vector_type(4))) float f32x4;

typedef const __attribute__((address_space(1))) void* gvptr;
typedef __attribute__((address_space(3))) void* lvptr;

static __device__ __forceinline__ short f2bf(float f) {
    unsigned u = __float_as_uint(f);
    unsigned r = (u + 0x7fffu + ((u >> 16) & 1u)) >> 16;   // RNE
    return (short)r;
}
// pack two fp32 -> bf16x2 dword (round-half-up)
static __device__ __forceinline__ unsigned pack2bf(float lo, float hi) {
    unsigned a = __float_as_uint(lo), b = __float_as_uint(hi);
    return ((a + 0x8000u) >> 16) | ((b + 0x8000u) & 0xffff0000u);
}

// ---------------------------------------------------------------------------
// Fused prep: blocks [0,4096) cast x -> bf16; [4096,7168) transpose+cast
// w_qkv; [7168,8192) transpose+cast w_proj.  One launch instead of three.
// ---------------------------------------------------------------------------
__global__ __launch_bounds__(256) void prep_kernel(
    const float* __restrict__ x, const float* __restrict__ wq,
    const float* __restrict__ wp,
    short* __restrict__ xb, short* __restrict__ wqb, short* __restrict__ wpb)
{
    const int bid = blockIdx.x;
    const int tid = threadIdx.x;
    if (bid < 4096) {
        size_t i = ((size_t)bid * 256 + tid) * 8;
        float4 a = *(const float4*)&x[i];
        float4 b = *(const float4*)&x[i + 4];
        bf16x8 o;
        o[0] = f2bf(a.x); o[1] = f2bf(a.y); o[2] = f2bf(a.z); o[3] = f2bf(a.w);
        o[4] = f2bf(b.x); o[5] = f2bf(b.y); o[6] = f2bf(b.z); o[7] = f2bf(b.w);
        *(bf16x8*)&xb[i] = o;
        return;
    }
    __shared__ float Ld[32][33];
    const float* in; short* outp; int C, tb;
    if (bid < 4096 + 3072) { tb = bid - 4096; in = wq; outp = wqb; C = LDQKV; }
    else                   { tb = bid - 7168; in = wp; outp = wpb; C = DIM; }
    const int R = DIM;
    const int ntx = C / 32;
    const int c0 = (tb % ntx) * 32, r0 = (tb / ntx) * 32;
    const int tx = tid & 31, ty = tid >> 5;
#pragma unroll
    for (int i = 0; i < 4; i++) {
        int r = ty + i * 8;
        Ld[r][tx] = in[(size_t)(r0 + r) * C + c0 + tx];
    }
    __syncthreads();
#pragma unroll
    for (int i = 0; i < 4; i++) {
        int rr = ty + i * 8;
        outp[(size_t)(c0 + rr) * R + r0 + tx] = f2bf(Ld[tx][rr]);
    }
}

// ---------------------------------------------------------------------------
// bf16 MFMA GEMM (m97 structure): 128x128 tile, BK=32, 4 waves 2x2, 4x4 acc.
// MODE 0: C = A@Bt^T + bias, fp32 out (proj).
// MODE 1: QKV with head-major scatter epilogue:
//   sec 0/1 (Q/K): dst[bh][t][d] bf16 ; sec 2 (V): Vth[bh][d][t] bf16,
//   reg-packed 8B stores (reg axis = consecutive t).
// ---------------------------------------------------------------------------
template<int MODE>
__global__ __launch_bounds__(256) void gemm_mfma_kernel(
    const short* __restrict__ A,    // [M x K] bf16
    const short* __restrict__ Bt,   // [N x K] bf16
    const float* __restrict__ bias, // [N] fp32
    float* __restrict__ Cf,         // MODE 0 out
    short* __restrict__ Qh, short* __restrict__ Kh, short* __restrict__ Vth,
    int M, int N, int K)
{
    __shared__ __align__(16) short As[128 * 32];
    __shared__ __align__(16) short Bs[128 * 32];

    const int tid  = threadIdx.x;
    const int w    = tid >> 6;
    const int lane = tid & 63;
    const int l16  = lane & 15;
    const int quad = lane >> 4;
    const int wm   = w >> 1;
    const int wn   = w & 1;
    const int m0   = blockIdx.y * 128;
    const int n0   = blockIdx.x * 128;

    f32x4 acc[4][4];
#pragma unroll
    for (int mi = 0; mi < 4; mi++)
#pragma unroll
        for (int ni = 0; ni < 4; ni++) acc[mi][ni] = (f32x4){0.f, 0.f, 0.f, 0.f};

    for (int kt = 0; kt < K; kt += 32) {
        __syncthreads();
#pragma unroll
        for (int r = 0; r < 2; r++) {
            int vi  = tid + r * 256;
            int row = vi >> 2;
            int kb  = (vi & 3) * 8;
            __builtin_amdgcn_global_load_lds(
                (gvptr)&A[(size_t)(m0 + row) * K + kt + kb],
                (lvptr)&As[vi * 8], 16, 0, 0);
        }
#pragma unroll
        for (int r = 0; r < 2; r++) {
            int vi  = tid + r * 256;
            int row = vi >> 2;
            int kb  = (vi & 3) * 8;
            __builtin_amdgcn_global_load_lds(
                (gvptr)&Bt[(size_t)(n0 + row) * K + kt + kb],
                (lvptr)&Bs[vi * 8], 16, 0, 0);
        }
        __syncthreads();

        bf16x8 af[4], bfr[4];
#pragma unroll
        for (int mi = 0; mi < 4; mi++)
            af[mi] = *(const bf16x8*)&As[(wm * 64 + mi * 16 + l16) * 32 + quad * 8];
#pragma unroll
        for (int ni = 0; ni < 4; ni++)
            bfr[ni] = *(const bf16x8*)&Bs[(wn * 64 + ni * 16 + l16) * 32 + quad * 8];
#pragma unroll
        for (int mi = 0; mi < 4; mi++)
#pragma unroll
            for (int ni = 0; ni < 4; ni++)
                acc[mi][ni] = __builtin_amdgcn_mfma_f32_16x16x32_bf16(
                    af[mi], bfr[ni], acc[mi][ni], 0, 0, 0);
    }

    if (MODE == 0) {
#pragma unroll
        for (int ni = 0; ni < 4; ni++) {
            int n = n0 + wn * 64 + ni * 16 + l16;
            float bv = bias[n];
#pragma unroll
            for (int mi = 0; mi < 4; mi++)
#pragma unroll
                for (int reg = 0; reg < 4; reg++) {
                    int m = m0 + wm * 64 + mi * 16 + quad * 4 + reg;
                    Cf[(size_t)m * N + n] = acc[mi][ni][reg] + bv;
                }
        }
    } else {
        const int b16 = (m0 >> 10) * 16;       // batch*16
        const int tB  = m0 & 1023;             // t base within batch
        const int sec = n0 >> 10;              // 0=Q 1=K 2=V (block-uniform)
#pragma unroll
        for (int ni = 0; ni < 4; ni++) {
            int n  = n0 + wn * 64 + ni * 16 + l16;
            int nl = n & 1023;
            int hh = nl >> 6, dd = nl & 63;
            float bv = bias[n];
            size_t base = (size_t)(b16 + hh) * (SEQ * HDIM);
            if (sec == 2) {
#pragma unroll
                for (int mi = 0; mi < 4; mi++) {
                    int t0 = tB + wm * 64 + mi * 16 + quad * 4;
                    float v0 = acc[mi][ni][0] + bv;
                    float v1 = acc[mi][ni][1] + bv;
                    float v2 = acc[mi][ni][2] + bv;
                    float v3 = acc[mi][ni][3] + bv;
                    *(uint2*)&Vth[base + (size_t)dd * SEQ + t0] =
                        make_uint2(pack2bf(v0, v1), pack2bf(v2, v3));
                }
            } else {
                short* dst = (sec == 0) ? Qh : Kh;
#pragma unroll
                for (int mi = 0; mi < 4; mi++)
#pragma unroll
                    for (int reg = 0; reg < 4; reg++) {
                        int t = tB + wm * 64 + mi * 16 + quad * 4 + reg;
                        dst[base + (size_t)t * HDIM + dd] =
                            f2bf(acc[mi][ni][reg] + bv);
                    }
            }
        }
    }
}

// ---------------------------------------------------------------------------
// Causal flash attention v4: head-major inputs, swapped-operand MFMA,
// static-max softmax, Q-tile 128, K-tile 64, fp32 acc.
// Double-buffered K/V LDS (LDK=64, XOR chunk swizzle slot=ch^(row&7)) ->
// ONE __syncthreads per k-tile.  LDS = 32K (KV dbuf) + 18K (QP) = 50.4 KB
// -> 3 blocks/CU.
// ---------------------------------------------------------------------------
#define LDP 72

__global__ __launch_bounds__(256, 3) void attn_kernel(
    const short* __restrict__ Qh, const short* __restrict__ Kh,
    const short* __restrict__ Vth, short* __restrict__ out)
{
    const int bh    = blockIdx.x;
    const int qtile = 7 - (int)blockIdx.y;      // longest blocks first
    const int b  = bh >> 4;
    const int h  = bh & 15;
    const int q0 = qtile * 128;
    const int tid  = threadIdx.x;
    const int w    = tid >> 6;
    const int lane = tid & 63;
    const int l16  = lane & 15;
    const int quad = lane >> 4;
    const int sw   = l16 & 7;                   // read-side swizzle key

    __shared__ __align__(16) short KsB[2 * 64 * 64];
    __shared__ __align__(16) short VtB[2 * 64 * 64];
    __shared__ __align__(16) short QP[128 * LDP];   // Q staging, then wave-private P

    // ---- stage Q (128 x 64 bf16, fully contiguous) ----
    const short* qbase = Qh + (size_t)bh * (SEQ * HDIM) + (size_t)q0 * HDIM;
#pragma unroll
    for (int s = 0; s < 4; s++) {
        int vi = tid + s * 256;
        int row = vi >> 3, d8 = (vi & 7) * 8;
        *(bf16x8*)&QP[row * LDP + d8] = *(const bf16x8*)&qbase[row * HDIM + d8];
    }
    __syncthreads();

    bf16x8 qfragT[2][2];
#pragma unroll
    for (int qb = 0; qb < 2; qb++)
#pragma unroll
        for (int ks = 0; ks < 2; ks++)
            qfragT[qb][ks] = *(const bf16x8*)
                &QP[(w * 32 + qb * 16 + l16) * LDP + ks * 32 + quad * 8];
    // From here QP rows are wave-private (P scratch).

    f32x4 o_accT[2][4];
#pragma unroll
    for (int qb = 0; qb < 2; qb++)
#pragma unroll
        for (int db = 0; db < 4; db++) o_accT[qb][db] = (f32x4){0.f, 0.f, 0.f, 0.f};
    float l_run[2] = {0.f, 0.f};

    const int nkt = 2 * qtile + 2;
    const short* kb0 = Kh  + (size_t)bh * (SEQ * HDIM);
    const short* vb0 = Vth + (size_t)bh * (SEQ * HDIM);

    const int srow = tid >> 3;          // staging row (with +32 for s=1)
    const int sch  = tid & 7;           // staging chunk
    const int sslot0 = (sch ^ (srow & 7)) * 8;
    const int sslot1 = (sch ^ ((srow + 32) & 7)) * 8;

    bf16x8 kreg[2], vreg[2];
    // stage tile 0
    kreg[0] = *(const bf16x8*)&kb0[(size_t)srow * HDIM + sch * 8];
    kreg[1] = *(const bf16x8*)&kb0[(size_t)(srow + 32) * HDIM + sch * 8];
    vreg[0] = *(const bf16x8*)&vb0[(size_t)srow * SEQ + sch * 8];
    vreg[1] = *(const bf16x8*)&vb0[(size_t)(srow + 32) * SEQ + sch * 8];
    *(bf16x8*)&KsB[srow * 64 + sslot0]        = kreg[0];
    *(bf16x8*)&KsB[(srow + 32) * 64 + sslot1] = kreg[1];
    *(bf16x8*)&VtB[srow * 64 + sslot0]        = vreg[0];
    *(bf16x8*)&VtB[(srow + 32) * 64 + sslot1] = vreg[1];

    for (int kt = 0; kt < nkt; kt++) {
        __syncthreads();                 // buf[cur] ready; buf[cur^1] free
        const int k0 = kt * 64;
        const short* Ks = &KsB[(kt & 1) * 4096];
        const short* Vt = &VtB[(kt & 1) * 4096];

        // prefetch next tile into registers (consumed at window bottom)
        if (kt + 1 < nkt) {
            const short* kb = kb0 + (size_t)(k0 + 64) * HDIM;
            const short* vb = vb0 + (k0 + 64);
            kreg[0] = *(const bf16x8*)&kb[(size_t)srow * HDIM + sch * 8];
            kreg[1] = *(const bf16x8*)&kb[(size_t)(srow + 32) * HDIM + sch * 8];
            vreg[0] = *(const bf16x8*)&vb[(size_t)srow * SEQ + sch * 8];
            vreg[1] = *(const bf16x8*)&vb[(size_t)(srow + 32) * SEQ + sch * 8];
        }

        // ---- S^T = K Q^T : A=K frag (m=key), B=Q frag (n=q) ----
        f32x4 sT[2][4];
#pragma unroll
        for (int qb = 0; qb < 2; qb++)
#pragma unroll
            for (int kb = 0; kb < 4; kb++) sT[qb][kb] = (f32x4){0.f, 0.f, 0.f, 0.f};
#pragma unroll
        for (int kb = 0; kb < 4; kb++) {
            bf16x8 kf0 = *(const bf16x8*)&Ks[(kb * 16 + l16) * 64 + ((0 + quad) ^ sw) * 8];
            bf16x8 kf1 = *(const bf16x8*)&Ks[(kb * 16 + l16) * 64 + ((4 + quad) ^ sw) * 8];
#pragma unroll
            for (int qb = 0; qb < 2; qb++) {
                sT[qb][kb] = __builtin_amdgcn_mfma_f32_16x16x32_bf16(
                    kf0, qfragT[qb][0], sT[qb][kb], 0, 0, 0);
                sT[qb][kb] = __builtin_amdgcn_mfma_f32_16x16x32_bf16(
                    kf1, qfragT[qb][1], sT[qb][kb], 0, 0, 0);
            }
        }

        // ---- exp2 (folded scale), causal mask (last 2 tiles), pack P ----
        const bool domask = (kt >= nkt - 2);
        const float c2 = 0.18033688011112042f;   // 0.125 * log2(e)
#pragma unroll
        for (int qb = 0; qb < 2; qb++) {
            const int q = q0 + w * 32 + qb * 16 + l16;
            float lsum = 0.f;
#pragma unroll
            for (int kb = 0; kb < 4; kb++) {
                float p[4];
#pragma unroll
                for (int r = 0; r < 4; r++) {
                    float e = exp2f(sT[qb][kb][r] * c2);
                    int key = k0 + kb * 16 + quad * 4 + r;
                    p[r] = (!domask || key <= q) ? e : 0.f;
                    lsum += p[r];
                }
                *(uint2*)&QP[(w * 32 + qb * 16 + l16) * LDP + kb * 16 + quad * 4] =
                    make_uint2(pack2bf(p[0], p[1]), pack2bf(p[2], p[3]));
            }
            lsum += __shfl_xor(lsum, 16, 64);
            lsum += __shfl_xor(lsum, 32, 64);
            l_run[qb] += lsum;
        }

        // ---- O^T += V^T P^T : A=Vt frag (m=d), B=P frag (n=q) ----
#pragma unroll
        for (int ks2 = 0; ks2 < 2; ks2++) {
            bf16x8 pf[2];
#pragma unroll
            for (int qb = 0; qb < 2; qb++)
                pf[qb] = *(const bf16x8*)
                    &QP[(w * 32 + qb * 16 + l16) * LDP + ks2 * 32 + quad * 8];
#pragma unroll
            for (int db = 0; db < 4; db++) {
                bf16x8 vf = *(const bf16x8*)
                    &Vt[(db * 16 + l16) * 64 + ((ks2 * 4 + quad) ^ sw) * 8];
#pragma unroll
                for (int qb = 0; qb < 2; qb++)
                    o_accT[qb][db] = __builtin_amdgcn_mfma_f32_16x16x32_bf16(
                        vf, pf[qb], o_accT[qb][db], 0, 0, 0);
            }
        }

        // ---- restage into the other buffer (no barrier needed here) ----
        if (kt + 1 < nkt) {
            short* Kn = &KsB[((kt + 1) & 1) * 4096];
            short* Vn = &VtB[((kt + 1) & 1) * 4096];
            *(bf16x8*)&Kn[srow * 64 + sslot0]        = kreg[0];
            *(bf16x8*)&Kn[(srow + 32) * 64 + sslot1] = kreg[1];
            *(bf16x8*)&Vn[srow * 64 + sslot0]        = vreg[0];
            *(bf16x8*)&Vn[(srow + 32) * 64 + sslot1] = vreg[1];
        }
    }

    // ---- epilogue: O^T/l, packed 8B stores ----
#pragma unroll
    for (int qb = 0; qb < 2; qb++) {
        const float inv = 1.f / l_run[qb];
        const int q = q0 + w * 32 + qb * 16 + l16;
        short* ob = out + (size_t)(b * SEQ + q) * DIM + h * HDIM;
#pragma unroll
        for (int db = 0; db < 4; db++) {
            float v0 = o_accT[qb][db][0] * inv;
            float v1 = o_accT[qb][db][1] * inv;
            float v2 = o_accT[qb][db][2] * inv;
            float v3 = o_accT[qb][db][3] * inv;
            *(uint2*)&ob[db * 16 + quad * 4] =
                make_uint2(pack2bf(v0, v1), pack2bf(v2, v3));
        }
    }
}

// ---------------------------------------------------------------------------
extern "C" void kernel_launch(void* const* d_in, const int* in_sizes, int n_in,
                              void* d_out, int out_size, void* d_ws, size_t ws_size,
                              hipStream_t stream)
{
    const float* x      = (const float*)d_in[0];
    const float* w_qkv  = (const float*)d_in[1];
    const float* b_qkv  = (const float*)d_in[2];
    const float* w_proj = (const float*)d_in[3];
    const float* b_proj = (const float*)d_in[4];
    float* out = (float*)d_out;

    const int M = BATCH * SEQ;  // 8192

    short* xb    = (short*)d_ws;                       // [8192 x 1024]
    short* wqb   = xb    + (size_t)M * DIM;            // [3072 x 1024]
    short* wpb   = wqb   + (size_t)LDQKV * DIM;        // [1024 x 1024]
    short* Qhb   = wpb   + (size_t)DIM * DIM;          // [128 x 1024 x 64]
    short* Khb   = Qhb   + (size_t)M * DIM;            // [128 x 1024 x 64]
    short* Vthb  = Khb   + (size_t)M * DIM;            // [128 x 64 x 1024]
    short* attnb = Vthb  + (size_t)M * DIM;            // [8192 x 1024]

    prep_kernel<<<8192, 256, 0, stream>>>(x, w_qkv, w_proj, xb, wqb, wpb);

    gemm_mfma_kernel<1><<<dim3(LDQKV / 128, M / 128), 256, 0, stream>>>(
        xb, wqb, b_qkv, nullptr, Qhb, Khb, Vthb, M, LDQKV, DIM);

    attn_kernel<<<dim3(BATCH * NH, SEQ / 128), 256, 0, stream>>>(
        Qhb, Khb, Vthb, attnb);

    gemm_mfma_kernel<0><<<dim3(DIM / 128, M / 128), 256, 0, stream>>>(
        attnb, wpb, b_proj, out, nullptr, nullptr, nullptr, M, DIM, DIM);
}